// Round 2
// baseline (262.751 us; speedup 1.0000x reference)
//
#include <hip/hip_runtime.h>

typedef _Float16 half8  __attribute__((ext_vector_type(8)));
typedef _Float16 half2v __attribute__((ext_vector_type(2)));
typedef float    f32x16 __attribute__((ext_vector_type(16)));
typedef float    f32x4v __attribute__((ext_vector_type(4)));

namespace {
constexpr int kB = 8, kH = 16, kS = 1024, kD = 64;
constexpr int QT  = 128;      // query rows per block (4 waves x 32)
constexpr int KT  = 64;       // keys per tile
constexpr int NKT = kS / KT;  // 16 tiles
constexpr int KST = 72;       // padded LDS row stride (elements) = 144 B (16B-aligned)
}

__global__ __launch_bounds__(256, 2)
void sdpa_logsig_kernel(const float* __restrict__ Qg_, const float* __restrict__ Kg_,
                        const float* __restrict__ Vg_, const void* __restrict__ Mg_,
                        float* __restrict__ Og_) {
  __shared__ _Float16 Klds[KT][KST];          // K tile   [key][d]
  __shared__ _Float16 Vlds[kD][KST];          // logsig(V)^T [d][key]
  __shared__ _Float16 Ptl[4][32][KST];        // per-wave P [q][key]

  const int t    = threadIdx.x;
  const int qblk = blockIdx.x;    // 0..7
  const int bh   = blockIdx.y;    // 0..127
  const int b    = bh >> 4;       // H = 16

  const float* Qg = Qg_ + ((size_t)bh * kS + (size_t)qblk * QT) * kD;
  const float* Kg = Kg_ + (size_t)bh * kS * kD;
  const float* Vg = Vg_ + (size_t)bh * kS * kD;
  float* Og = Og_ + ((size_t)bh * kS + (size_t)qblk * QT) * kD;

  const int l    = t & 63;
  const int w    = t >> 6;        // wave 0..3
  const int h    = l >> 5;        // lane half
  const int q31  = l & 31;
  const int qloc = w * 32 + q31;  // this lane's query row within block
  const int qg   = qblk * QT + qloc;  // global q row

  // staging decomposition: thread t covers key = t>>2, d in [16*(t&3), +16)
  const int skey = t >> 2;
  const int sj   = t & 3;
  const int sd4  = sj << 4;

  // ---- mask dtype probe (uniform): int32 {0,1} storage has all bytes %4!=0 zero;
  //      numpy-bool bytes fail this with P ~ 2^-48. Harness doc says integer->int*.
  unsigned pacc = 0;
  {
    const unsigned* mprobe = (const unsigned*)Mg_;
    #pragma unroll
    for (int i = 0; i < 16; ++i) pacc |= mprobe[i] & 0xFFFFFF00u;
  }
  const bool mask_i32 = (pacc == 0);
  const size_t moff0 = (size_t)b * kS * kS + (size_t)qg * kS + 4 * h;  // element offset

  // ---- Q fragments in registers, pre-scaled by 1/sqrt(64) (exact pow2) ----
  half8 qf[4];
  {
    const float* qp = Qg + (size_t)qloc * kD + 8 * h;
    #pragma unroll
    for (int c = 0; c < 4; ++c) {
      f32x4v x = *(const f32x4v*)(qp + 16 * c);
      f32x4v y = *(const f32x4v*)(qp + 16 * c + 4);
      half8 f;
      #pragma unroll
      for (int j = 0; j < 4; ++j) {
        f[j]     = (_Float16)(x[j] * 0.125f);
        f[j + 4] = (_Float16)(y[j] * 0.125f);
      }
      qf[c] = f;
    }
  }

  f32x16 oacc[2];
  #pragma unroll
  for (int d = 0; d < 2; ++d) {
    #pragma unroll
    for (int i = 0; i < 16; ++i) oacc[d][i] = 0.f;
  }
  float mrun = -1e9f, lrun = 0.f;

  for (int kt = 0; kt < NKT; ++kt) {
    __syncthreads();   // previous tile's LDS reads done before overwrite

    // ---- stage K tile (f32 -> f16) ----
    {
      const float* kp = Kg + (size_t)(kt * KT + skey) * kD + sd4;
      f32x4v a0 = *(const f32x4v*)(kp);
      f32x4v a1 = *(const f32x4v*)(kp + 4);
      f32x4v a2 = *(const f32x4v*)(kp + 8);
      f32x4v a3 = *(const f32x4v*)(kp + 12);
      half8 h0, h1;
      #pragma unroll
      for (int j = 0; j < 4; ++j) {
        h0[j] = (_Float16)a0[j]; h0[j + 4] = (_Float16)a1[j];
        h1[j] = (_Float16)a2[j]; h1[j + 4] = (_Float16)a3[j];
      }
      *(half8*)&Klds[skey][sd4]     = h0;
      *(half8*)&Klds[skey][sd4 + 8] = h1;
    }

    // ---- stage logsigmoid(V)^T; chunk-rotated to spread write banks ----
    {
      const float* vp = Vg + (size_t)(kt * KT + skey) * kD + sd4;
      _Float16 lv[16];                        // compile-time indices -> registers
      #pragma unroll
      for (int i = 0; i < 4; ++i) {
        const int c = (i + sj) & 3;           // runtime address rotation only
        f32x4v xv = *(const f32x4v*)(vp + 4 * c);
        #pragma unroll
        for (int jj = 0; jj < 4; ++jj) {
          float x  = xv[jj];
          float ls = fminf(x, 0.f) - __logf(1.f + __expf(-fabsf(x)));
          lv[4 * i + jj] = (_Float16)ls;
        }
      }
      #pragma unroll
      for (int i = 0; i < 4; ++i) {
        const int c = (i + sj) & 3;
        #pragma unroll
        for (int jj = 0; jj < 4; ++jj)
          Vlds[sd4 + 4 * c + jj][skey] = lv[4 * i + jj];
      }
    }

    // ---- fetch this lane's mask quads for its q-row (global, L3-served) ----
    // quad i = 4*ks+m4 covers keys kt*64 + 32*ks + 8*m4 + 4*h + {0..3}
    unsigned mq[8];
    if (mask_i32) {
      const int* mp = (const int*)Mg_ + moff0 + kt * KT;
      #pragma unroll
      for (int i = 0; i < 8; ++i) {
        const int4 mv = *(const int4*)(mp + 32 * (i >> 2) + 8 * (i & 3));
        mq[i] = (unsigned)(mv.x & 1) | ((unsigned)(mv.y & 1) << 8) |
                ((unsigned)(mv.z & 1) << 16) | ((unsigned)(mv.w & 1) << 24);
      }
    } else {
      const unsigned char* mp = (const unsigned char*)Mg_ + moff0 + kt * KT;
      #pragma unroll
      for (int i = 0; i < 8; ++i)
        mq[i] = *(const unsigned*)(mp + 32 * (i >> 2) + 8 * (i & 3));
    }
    __syncthreads();

    // ---- S^T = K . Q^T  (swapped: lane holds one q-row's scores) ----
    f32x16 sacc[2];
    #pragma unroll
    for (int ks = 0; ks < 2; ++ks) {
      #pragma unroll
      for (int i = 0; i < 16; ++i) sacc[ks][i] = 0.f;
    }
    #pragma unroll
    for (int ks = 0; ks < 2; ++ks) {
      #pragma unroll
      for (int c = 0; c < 4; ++c) {
        half8 kf = *(const half8*)&Klds[32 * ks + q31][16 * c + 8 * h];
        sacc[ks] = __builtin_amdgcn_mfma_f32_32x32x16_f16(kf, qf[c], sacc[ks], 0, 0, 0);
      }
    }

    // ---- mask + running row max (key for reg 4*m4+r: 32*ks + 8*m4 + 4*h + r) ----
    float smax = -1e9f;
    #pragma unroll
    for (int ks = 0; ks < 2; ++ks) {
      #pragma unroll
      for (int m4 = 0; m4 < 4; ++m4) {
        const unsigned mw = mq[4 * ks + m4];
        #pragma unroll
        for (int r = 0; r < 4; ++r) {
          float s = sacc[ks][4 * m4 + r];
          s = ((mw >> (8 * r)) & 0xffu) ? s : -1e9f;   // where(mask, s, -1e9)
          sacc[ks][4 * m4 + r] = s;
          smax = fmaxf(smax, s);
        }
      }
    }
    smax = fmaxf(smax, __shfl_xor(smax, 32));
    const float mnew = fmaxf(mrun, smax);
    const float corr = __expf(mrun - mnew);
    mrun = mnew;

    // ---- P = exp(S - m), f16-rounded; l-sum from the rounded values ----
    float psum = 0.f;
    #pragma unroll
    for (int ks = 0; ks < 2; ++ks) {
      #pragma unroll
      for (int m4 = 0; m4 < 4; ++m4) {
        _Float16 p0 = (_Float16)__expf(sacc[ks][4 * m4 + 0] - mnew);
        _Float16 p1 = (_Float16)__expf(sacc[ks][4 * m4 + 1] - mnew);
        _Float16 p2 = (_Float16)__expf(sacc[ks][4 * m4 + 2] - mnew);
        _Float16 p3 = (_Float16)__expf(sacc[ks][4 * m4 + 3] - mnew);
        psum += (float)p0 + (float)p1 + (float)p2 + (float)p3;
        half2v p01; p01[0] = p0; p01[1] = p1;
        half2v p23; p23[0] = p2; p23[1] = p3;
        const int key0 = 32 * ks + 8 * m4 + 4 * h;
        *(half2v*)&Ptl[w][q31][key0]     = p01;
        *(half2v*)&Ptl[w][q31][key0 + 2] = p23;
      }
    }
    psum += __shfl_xor(psum, 32);
    lrun = lrun * corr + psum;
    #pragma unroll
    for (int d = 0; d < 2; ++d) {
      #pragma unroll
      for (int i = 0; i < 16; ++i) oacc[d][i] *= corr;
    }

    // ---- O^T += logsig(V)^T . P^T ----
    half8 pf[4];
    #pragma unroll
    for (int c2 = 0; c2 < 4; ++c2)
      pf[c2] = *(const half8*)&Ptl[w][q31][16 * c2 + 8 * h];
    #pragma unroll
    for (int ds = 0; ds < 2; ++ds) {
      #pragma unroll
      for (int c2 = 0; c2 < 4; ++c2) {
        half8 vf = *(const half8*)&Vlds[32 * ds + q31][16 * c2 + 8 * h];
        oacc[ds] = __builtin_amdgcn_mfma_f32_32x32x16_f16(vf, pf[c2], oacc[ds], 0, 0, 0);
      }
    }
  }

  // ---- epilogue: out = exp(O / l), coalesced float4 stores ----
  const float invl = 1.f / lrun;
  float* op = Og + (size_t)qloc * kD;
  #pragma unroll
  for (int ds = 0; ds < 2; ++ds) {
    #pragma unroll
    for (int m4 = 0; m4 < 4; ++m4) {
      f32x4v v;
      #pragma unroll
      for (int r = 0; r < 4; ++r)
        v[r] = __expf(oacc[ds][4 * m4 + r] * invl);
      *(f32x4v*)&op[32 * ds + 8 * m4 + 4 * h] = v;
    }
  }
}

extern "C" void kernel_launch(void* const* d_in, const int* in_sizes, int n_in,
                              void* d_out, int out_size, void* d_ws, size_t ws_size,
                              hipStream_t stream) {
  const float* Q = (const float*)d_in[0];
  const float* K = (const float*)d_in[1];
  const float* V = (const float*)d_in[2];
  const void*  M = (const void*)d_in[3];   // int32 per harness contract; probe hedges
  float* O = (float*)d_out;
  dim3 grid(kS / QT, kB * kH);   // (8, 128)
  sdpa_logsig_kernel<<<grid, dim3(256), 0, stream>>>(Q, K, V, M, O);
}

// Round 4
// 224.119 us; speedup vs baseline: 1.1724x; 1.1724x over previous
//
#include <hip/hip_runtime.h>

typedef _Float16 half8  __attribute__((ext_vector_type(8)));
typedef _Float16 half4v __attribute__((ext_vector_type(4)));
typedef _Float16 half2v __attribute__((ext_vector_type(2)));
typedef float    f32x16 __attribute__((ext_vector_type(16)));
typedef float    f32x4v __attribute__((ext_vector_type(4)));

namespace {
constexpr int kB = 8, kH = 16, kS = 1024, kD = 64;
constexpr int QT  = 128;      // query rows per block (4 waves x 32)
constexpr int KT  = 64;       // keys per tile
constexpr int NKT = kS / KT;  // 16 tiles
constexpr int KST = 72;       // padded LDS row stride (elems) = 144 B, 16B-aligned
// workspace layout
constexpr size_t KH_OFF = 0;                                   // K f16 [bh][k][d], 16 MiB
constexpr size_t VT_OFF = (size_t)kB * kH * kS * kD * 2;       // lsV^T f16 [bh][d][k], 16 MiB
constexpr size_t MB_OFF = VT_OFF * 2;                          // mask bits [b][q][32 u32], 1 MiB
constexpr size_t WS_NEED = MB_OFF + (size_t)kB * kS * (kS / 32) * 4;
}

__device__ __forceinline__ float logsig(float x) {
  return fminf(x, 0.f) - __logf(1.f + __expf(-fabsf(x)));
}

// ---------------- pre-pass: K->f16, logsig(V)^T->f16, mask->bits ----------------
__global__ __launch_bounds__(256, 4)
void pre_kernel(const float* __restrict__ K, const float* __restrict__ V,
                const int* __restrict__ M, _Float16* __restrict__ Kh,
                _Float16* __restrict__ Vt, unsigned* __restrict__ Mb) {
  const int blk = blockIdx.x, t = threadIdx.x;
  if (blk < 8192) {
    // K convert: 4 f32 per thread, fully coalesced
    const size_t idx = ((size_t)blk * 256 + t) * 4;
    f32x4v x = *(const f32x4v*)(K + idx);
    half4v o;
    #pragma unroll
    for (int j = 0; j < 4; ++j) o[j] = (_Float16)x[j];
    *(half4v*)(Kh + idx) = o;
  } else if (blk < 10240) {
    // logsig(V), transposed per 64x64 tile via LDS
    __shared__ _Float16 T[64][72];
    const int bb = blk - 8192;
    const int bh = bb >> 4, ktt = bb & 15;
    const int key = t >> 2, dc = (t & 3) << 4;
    const float* vp = V + (((size_t)bh * kS + ktt * KT + key)) * kD + dc;
    #pragma unroll
    for (int i = 0; i < 4; ++i) {
      f32x4v x = *(const f32x4v*)(vp + 4 * i);
      #pragma unroll
      for (int j = 0; j < 4; ++j) T[dc + 4 * i + j][key] = (_Float16)logsig(x[j]);
    }
    __syncthreads();
    const int d = t >> 2, kc = (t & 3) << 4;
    half8 r0 = *(const half8*)&T[d][kc];
    half8 r1 = *(const half8*)&T[d][kc + 8];
    _Float16* op = Vt + ((size_t)bh * kD + d) * kS + ktt * KT + kc;
    *(half8*)op = r0;
    *(half8*)(op + 8) = r1;
  } else {
    // mask pack: one u32 word (32 keys) per thread
    const int wi = (blk - 10240) * 256 + t;           // 0..262143
    const int row = wi >> 5;                          // b*1024 + q
    const int wrd = wi & 31;
    const int* mp = M + (size_t)row * kS + wrd * 32;
    unsigned bits = 0;
    #pragma unroll
    for (int i = 0; i < 8; ++i) {
      const int4 v = *(const int4*)(mp + 4 * i);
      bits |= (unsigned)(v.x & 1) << (4 * i) | (unsigned)(v.y & 1) << (4 * i + 1) |
              (unsigned)(v.z & 1) << (4 * i + 2) | (unsigned)(v.w & 1) << (4 * i + 3);
    }
    Mb[wi] = bits;
  }
}

// ---------------- main fused attention ----------------
__global__ __launch_bounds__(256, 4)
void sdpa_main(const float* __restrict__ Qg_, const _Float16* __restrict__ Kh,
               const _Float16* __restrict__ Vt, const unsigned* __restrict__ Mb,
               float* __restrict__ Og_) {
  __shared__ _Float16 Klds[KT][KST];     // K tile [key][d]
  __shared__ _Float16 Vlds[kD][KST];     // lsV^T tile [d][key]
  __shared__ _Float16 Ptl[4][32][KST];   // per-wave P [q][key]

  const int t = threadIdx.x;
  // XCD swizzle: each XCD gets one batch (mask + 16 heads' K/V stay in its L2)
  const int n   = blockIdx.x;
  const int xcd = n & 7, c = n >> 3;
  const int bh  = (xcd << 4) | (c >> 3);
  const int qblk = c & 7;
  const int b   = bh >> 4;

  const float* Qg = Qg_ + ((size_t)bh * kS + (size_t)qblk * QT) * kD;
  float* Og = Og_ + ((size_t)bh * kS + (size_t)qblk * QT) * kD;

  const int l    = t & 63;
  const int w    = t >> 6;
  const int h    = l >> 5;
  const int q31  = l & 31;
  const int qloc = w * 32 + q31;
  const int qg   = qblk * QT + qloc;

  const int skey = t >> 2;           // staging: key row
  const int sd4  = (t & 3) << 4;     // staging: d chunk
  const int vrow = t >> 2;           // V staging: d row
  const int vkc  = (t & 3) << 4;     // V staging: key chunk

  const _Float16* kbase = Kh + ((size_t)bh * kS + skey) * kD + sd4;
  const _Float16* vbase = Vt + ((size_t)bh * kD + vrow) * kS + vkc;
  const unsigned* mbase = Mb + ((size_t)(b * kS + qg)) * 32;

  // Q fragments, pre-scaled by 1/8
  half8 qf[4];
  {
    const float* qp = Qg + (size_t)qloc * kD + 8 * h;
    #pragma unroll
    for (int cc = 0; cc < 4; ++cc) {
      f32x4v x = *(const f32x4v*)(qp + 16 * cc);
      f32x4v y = *(const f32x4v*)(qp + 16 * cc + 4);
      half8 f;
      #pragma unroll
      for (int j = 0; j < 4; ++j) {
        f[j]     = (_Float16)(x[j] * 0.125f);
        f[j + 4] = (_Float16)(y[j] * 0.125f);
      }
      qf[cc] = f;
    }
  }

  f32x16 oacc[2];
  #pragma unroll
  for (int d = 0; d < 2; ++d) {
    #pragma unroll
    for (int i = 0; i < 16; ++i) oacc[d][i] = 0.f;
  }
  float mrun = -1e9f, lrun = 0.f;

  // prologue: prefetch tile 0 into registers
  uint4 kreg0 = *(const uint4*)(kbase);
  uint4 kreg1 = *(const uint4*)(kbase + 8);
  uint4 vreg0 = *(const uint4*)(vbase);
  uint4 vreg1 = *(const uint4*)(vbase + 8);
  uint2 mreg  = *(const uint2*)(mbase);

  for (int kt = 0; kt < NKT; ++kt) {
    __syncthreads();   // previous tile's LDS reads complete

    *(uint4*)&Klds[skey][sd4]     = kreg0;
    *(uint4*)&Klds[skey][sd4 + 8] = kreg1;
    *(uint4*)&Vlds[vrow][vkc]     = vreg0;
    *(uint4*)&Vlds[vrow][vkc + 8] = vreg1;

    // nibble per quad: quad i=(ks=i>>2, m4=i&3) covers keys 32ks+8m4+4h+{0..3}
    unsigned nib[8];
    #pragma unroll
    for (int i = 0; i < 8; ++i) {
      const unsigned wv = (i >> 2) ? mreg.y : mreg.x;
      nib[i] = (wv >> (8 * (i & 3) + 4 * h)) & 0xFu;
    }

    if (kt + 1 < NKT) {  // prefetch next tile (latency hidden under compute)
      const size_t ko = (size_t)(kt + 1) * KT * kD;
      kreg0 = *(const uint4*)(kbase + ko);
      kreg1 = *(const uint4*)(kbase + ko + 8);
      vreg0 = *(const uint4*)(vbase + (kt + 1) * KT);
      vreg1 = *(const uint4*)(vbase + (kt + 1) * KT + 8);
      mreg  = *(const uint2*)(mbase + (kt + 1) * 2);
    }
    __syncthreads();

    // S^T = K . Q^T
    f32x16 sacc[2];
    #pragma unroll
    for (int ks = 0; ks < 2; ++ks) {
      #pragma unroll
      for (int i = 0; i < 16; ++i) sacc[ks][i] = 0.f;
    }
    #pragma unroll
    for (int ks = 0; ks < 2; ++ks) {
      #pragma unroll
      for (int cc = 0; cc < 4; ++cc) {
        half8 kf = *(const half8*)&Klds[32 * ks + q31][16 * cc + 8 * h];
        sacc[ks] = __builtin_amdgcn_mfma_f32_32x32x16_f16(kf, qf[cc], sacc[ks], 0, 0, 0);
      }
    }

    // mask + running max
    float smax = -1e9f;
    #pragma unroll
    for (int ks = 0; ks < 2; ++ks) {
      #pragma unroll
      for (int m4 = 0; m4 < 4; ++m4) {
        const unsigned nb = nib[4 * ks + m4];
        #pragma unroll
        for (int r = 0; r < 4; ++r) {
          float s = sacc[ks][4 * m4 + r];
          s = (nb & (1u << r)) ? s : -1e9f;
          sacc[ks][4 * m4 + r] = s;
          smax = fmaxf(smax, s);
        }
      }
    }
    smax = fmaxf(smax, __shfl_xor(smax, 32));
    const float mnew = fmaxf(mrun, smax);
    const float corr = __expf(mrun - mnew);
    mrun = mnew;

    // P = exp(S - m) -> f16 via LDS round-trip; l-sum in f32
    float psum = 0.f;
    #pragma unroll
    for (int ks = 0; ks < 2; ++ks) {
      #pragma unroll
      for (int m4 = 0; m4 < 4; ++m4) {
        float e0 = __expf(sacc[ks][4 * m4 + 0] - mnew);
        float e1 = __expf(sacc[ks][4 * m4 + 1] - mnew);
        float e2 = __expf(sacc[ks][4 * m4 + 2] - mnew);
        float e3 = __expf(sacc[ks][4 * m4 + 3] - mnew);
        psum += (e0 + e1) + (e2 + e3);
        half2v p01; p01[0] = (_Float16)e0; p01[1] = (_Float16)e1;
        half2v p23; p23[0] = (_Float16)e2; p23[1] = (_Float16)e3;
        const int key0 = 32 * ks + 8 * m4 + 4 * h;
        *(half2v*)&Ptl[w][q31][key0]     = p01;
        *(half2v*)&Ptl[w][q31][key0 + 2] = p23;
      }
    }
    psum += __shfl_xor(psum, 32);
    lrun = lrun * corr + psum;
    #pragma unroll
    for (int d = 0; d < 2; ++d) {
      #pragma unroll
      for (int i = 0; i < 16; ++i) oacc[d][i] *= corr;
    }

    // O^T += lsV^T . P^T
    half8 pf[4];
    #pragma unroll
    for (int c2 = 0; c2 < 4; ++c2)
      pf[c2] = *(const half8*)&Ptl[w][q31][16 * c2 + 8 * h];
    #pragma unroll
    for (int ds = 0; ds < 2; ++ds) {
      #pragma unroll
      for (int c2 = 0; c2 < 4; ++c2) {
        half8 vf = *(const half8*)&Vlds[32 * ds + q31][16 * c2 + 8 * h];
        oacc[ds] = __builtin_amdgcn_mfma_f32_32x32x16_f16(vf, pf[c2], oacc[ds], 0, 0, 0);
      }
    }
  }

  // epilogue: out = exp(O / l)
  const float invl = 1.f / lrun;
  float* op = Og + (size_t)qloc * kD;
  #pragma unroll
  for (int ds = 0; ds < 2; ++ds) {
    #pragma unroll
    for (int m4 = 0; m4 < 4; ++m4) {
      f32x4v v;
      #pragma unroll
      for (int r = 0; r < 4; ++r)
        v[r] = __expf(oacc[ds][4 * m4 + r] * invl);
      *(f32x4v*)&op[32 * ds + 8 * m4 + 4 * h] = v;
    }
  }
}

// ---------------- fallback (round-2 kernel, passed): used if ws too small ----------------
__global__ __launch_bounds__(256, 2)
void sdpa_logsig_kernel(const float* __restrict__ Qg_, const float* __restrict__ Kg_,
                        const float* __restrict__ Vg_, const void* __restrict__ Mg_,
                        float* __restrict__ Og_) {
  __shared__ _Float16 Klds[KT][KST];
  __shared__ _Float16 Vlds[kD][KST];
  __shared__ _Float16 Ptl[4][32][KST];

  const int t = threadIdx.x;
  const int qblk = blockIdx.x;
  const int bh = blockIdx.y;
  const int b = bh >> 4;

  const float* Qg = Qg_ + ((size_t)bh * kS + (size_t)qblk * QT) * kD;
  const float* Kg = Kg_ + (size_t)bh * kS * kD;
  const float* Vg = Vg_ + (size_t)bh * kS * kD;
  float* Og = Og_ + ((size_t)bh * kS + (size_t)qblk * QT) * kD;

  const int l = t & 63, w = t >> 6, h = l >> 5, q31 = l & 31;
  const int qloc = w * 32 + q31;
  const int qg = qblk * QT + qloc;
  const int skey = t >> 2, sj = t & 3, sd4 = sj << 4;

  unsigned pacc = 0;
  {
    const unsigned* mprobe = (const unsigned*)Mg_;
    #pragma unroll
    for (int i = 0; i < 16; ++i) pacc |= mprobe[i] & 0xFFFFFF00u;
  }
  const bool mask_i32 = (pacc == 0);
  const size_t moff0 = (size_t)b * kS * kS + (size_t)qg * kS + 4 * h;

  half8 qf[4];
  {
    const float* qp = Qg + (size_t)qloc * kD + 8 * h;
    #pragma unroll
    for (int cc = 0; cc < 4; ++cc) {
      f32x4v x = *(const f32x4v*)(qp + 16 * cc);
      f32x4v y = *(const f32x4v*)(qp + 16 * cc + 4);
      half8 f;
      #pragma unroll
      for (int j = 0; j < 4; ++j) { f[j] = (_Float16)(x[j] * 0.125f); f[j + 4] = (_Float16)(y[j] * 0.125f); }
      qf[cc] = f;
    }
  }
  f32x16 oacc[2];
  #pragma unroll
  for (int d = 0; d < 2; ++d) {
    #pragma unroll
    for (int i = 0; i < 16; ++i) oacc[d][i] = 0.f;
  }
  float mrun = -1e9f, lrun = 0.f;

  for (int kt = 0; kt < NKT; ++kt) {
    __syncthreads();
    {
      const float* kp = Kg + (size_t)(kt * KT + skey) * kD + sd4;
      f32x4v a0 = *(const f32x4v*)(kp);     f32x4v a1 = *(const f32x4v*)(kp + 4);
      f32x4v a2 = *(const f32x4v*)(kp + 8); f32x4v a3 = *(const f32x4v*)(kp + 12);
      half8 h0, h1;
      #pragma unroll
      for (int j = 0; j < 4; ++j) { h0[j] = (_Float16)a0[j]; h0[j+4] = (_Float16)a1[j]; h1[j] = (_Float16)a2[j]; h1[j+4] = (_Float16)a3[j]; }
      *(half8*)&Klds[skey][sd4] = h0; *(half8*)&Klds[skey][sd4 + 8] = h1;
    }
    {
      const float* vp = Vg + (size_t)(kt * KT + skey) * kD + sd4;
      _Float16 lv[16];
      #pragma unroll
      for (int i = 0; i < 4; ++i) {
        const int cc = (i + sj) & 3;
        f32x4v xv = *(const f32x4v*)(vp + 4 * cc);
        #pragma unroll
        for (int jj = 0; jj < 4; ++jj) lv[4 * i + jj] = (_Float16)logsig(xv[jj]);
      }
      #pragma unroll
      for (int i = 0; i < 4; ++i) {
        const int cc = (i + sj) & 3;
        #pragma unroll
        for (int jj = 0; jj < 4; ++jj) Vlds[sd4 + 4 * cc + jj][skey] = lv[4 * i + jj];
      }
    }
    unsigned mq[8];
    if (mask_i32) {
      const int* mp = (const int*)Mg_ + moff0 + kt * KT;
      #pragma unroll
      for (int i = 0; i < 8; ++i) {
        const int4 mv = *(const int4*)(mp + 32 * (i >> 2) + 8 * (i & 3));
        mq[i] = (unsigned)(mv.x & 1) | ((unsigned)(mv.y & 1) << 8) |
                ((unsigned)(mv.z & 1) << 16) | ((unsigned)(mv.w & 1) << 24);
      }
    } else {
      const unsigned char* mp = (const unsigned char*)Mg_ + moff0 + kt * KT;
      #pragma unroll
      for (int i = 0; i < 8; ++i) mq[i] = *(const unsigned*)(mp + 32 * (i >> 2) + 8 * (i & 3));
    }
    __syncthreads();

    f32x16 sacc[2];
    #pragma unroll
    for (int ks = 0; ks < 2; ++ks) {
      #pragma unroll
      for (int i = 0; i < 16; ++i) sacc[ks][i] = 0.f;
    }
    #pragma unroll
    for (int ks = 0; ks < 2; ++ks) {
      #pragma unroll
      for (int cc = 0; cc < 4; ++cc) {
        half8 kf = *(const half8*)&Klds[32 * ks + q31][16 * cc + 8 * h];
        sacc[ks] = __builtin_amdgcn_mfma_f32_32x32x16_f16(kf, qf[cc], sacc[ks], 0, 0, 0);
      }
    }
    float smax = -1e9f;
    #pragma unroll
    for (int ks = 0; ks < 2; ++ks) {
      #pragma unroll
      for (int m4 = 0; m4 < 4; ++m4) {
        const unsigned mw = mq[4 * ks + m4];
        #pragma unroll
        for (int r = 0; r < 4; ++r) {
          float s = sacc[ks][4 * m4 + r];
          s = ((mw >> (8 * r)) & 0xffu) ? s : -1e9f;
          sacc[ks][4 * m4 + r] = s;
          smax = fmaxf(smax, s);
        }
      }
    }
    smax = fmaxf(smax, __shfl_xor(smax, 32));
    const float mnew = fmaxf(mrun, smax);
    const float corr = __expf(mrun - mnew);
    mrun = mnew;
    float psum = 0.f;
    #pragma unroll
    for (int ks = 0; ks < 2; ++ks) {
      #pragma unroll
      for (int m4 = 0; m4 < 4; ++m4) {
        _Float16 p0 = (_Float16)__expf(sacc[ks][4*m4+0] - mnew);
        _Float16 p1 = (_Float16)__expf(sacc[ks][4*m4+1] - mnew);
        _Float16 p2 = (_Float16)__expf(sacc[ks][4*m4+2] - mnew);
        _Float16 p3 = (_Float16)__expf(sacc[ks][4*m4+3] - mnew);
        psum += (float)p0 + (float)p1 + (float)p2 + (float)p3;
        half2v p01; p01[0] = p0; p01[1] = p1;
        half2v p23; p23[0] = p2; p23[1] = p3;
        const int key0 = 32 * ks + 8 * m4 + 4 * h;
        *(half2v*)&Ptl[w][q31][key0] = p01;
        *(half2v*)&Ptl[w][q31][key0 + 2] = p23;
      }
    }
    psum += __shfl_xor(psum, 32);
    lrun = lrun * corr + psum;
    #pragma unroll
    for (int d = 0; d < 2; ++d) {
      #pragma unroll
      for (int i = 0; i < 16; ++i) oacc[d][i] *= corr;
    }

    half8 pf[4];
    #pragma unroll
    for (int c2 = 0; c2 < 4; ++c2) pf[c2] = *(const half8*)&Ptl[w][q31][16 * c2 + 8 * h];
    #pragma unroll
    for (int ds = 0; ds < 2; ++ds) {
      #pragma unroll
      for (int c2 = 0; c2 < 4; ++c2) {
        half8 vf = *(const half8*)&Vlds[32 * ds + q31][16 * c2 + 8 * h];
        oacc[ds] = __builtin_amdgcn_mfma_f32_32x32x16_f16(vf, pf[c2], oacc[ds], 0, 0, 0);
      }
    }
  }
  const float invl = 1.f / lrun;
  float* op = Og + (size_t)qloc * kD;
  #pragma unroll
  for (int ds = 0; ds < 2; ++ds) {
    #pragma unroll
    for (int m4 = 0; m4 < 4; ++m4) {
      f32x4v v;
      #pragma unroll
      for (int r = 0; r < 4; ++r) v[r] = __expf(oacc[ds][4 * m4 + r] * invl);
      *(f32x4v*)&op[32 * ds + 8 * m4 + 4 * h] = v;
    }
  }
}

extern "C" void kernel_launch(void* const* d_in, const int* in_sizes, int n_in,
                              void* d_out, int out_size, void* d_ws, size_t ws_size,
                              hipStream_t stream) {
  const float* Q = (const float*)d_in[0];
  const float* K = (const float*)d_in[1];
  const float* V = (const float*)d_in[2];
  float* O = (float*)d_out;
  if (ws_size >= WS_NEED) {
    _Float16* Kh = (_Float16*)((char*)d_ws + KH_OFF);
    _Float16* Vt = (_Float16*)((char*)d_ws + VT_OFF);
    unsigned* Mb = (unsigned*)((char*)d_ws + MB_OFF);
    pre_kernel<<<11264, 256, 0, stream>>>(K, V, (const int*)d_in[3], Kh, Vt, Mb);
    sdpa_main<<<1024, 256, 0, stream>>>(Q, Kh, Vt, Mb, O);
  } else {
    sdpa_logsig_kernel<<<dim3(kS / QT, kB * kH), 256, 0, stream>>>(Q, K, V, d_in[3], O);
  }
}